// Round 8
// baseline (288.463 us; speedup 1.0000x reference)
//
#include <hip/hip_runtime.h>
#include <math.h>

#define WSZ 11
#define PAD 5
#define TX 32
#define TY 24
#define NY 6                 // y-tiles per block: 144 rows/block, 2160/144 = 15
#define IY (TY + 2*PAD)      // 34
#define RX 4                 // h-pass: 4 output px per task
#define NTASK0 (IY * 8)      // 272 tasks (s==0: full 34 rows)
#define NTASK1 (TY * 8)      // 192 tasks (s>0: only 24 new rows)
#define SEG (RX + 2*PAD)     // 14 input floats per task
#define RY 3                 // v-pass rows per thread (8 groups x 3 = 24)
#define SA 33                // sHA row stride in float4 (odd -> rotating banks)

typedef float v2f __attribute__((ext_vector_type(2)));

struct W11 { float w[WSZ]; };

// R11 base (sum/diff 4-channel, rolling halo, TX=32/TY=24/NY=6 -> 106us)
// + R16 register prefetch. R12-R15 eliminated lane-fill, occupancy cap,
// LDS conflicts/traffic and barrier count as the idle source; the remaining
// candidate is Phase A global-load latency (10 loads issued then immediately
// consumed, all waves stalling together). R16 issues each thread's
// tile-(s+1) task loads BEFORE Phase B(s): consumption happens two barriers
// later, so B(s)+shift (~1000 VALU cycles) hides the ~200-900 cycle latency,
// and the vmcnt(0) folded into the end-of-B barrier is then free.
// LDS layout / barriers / per-px math bit-identical to R11. +40 VGPR.
__global__ __launch_bounds__(256, 4) void ssim_l1_kernel(
    const float* __restrict__ pred, const float* __restrict__ targ,
    W11 wt, float2* __restrict__ partials)
{
    constexpr int H = 2160, W = 3840;
    __shared__ float4 sHA[IY][SA];   // {hs, hd, hss, hdd}   17.95 KB

    const int c    = blockIdx.z;
    const int gx0  = blockIdx.x * TX;
    const int base = blockIdx.y * (TY * NY);   // first output row of block
    const size_t plane = (size_t)H * W;
    const float* p = pred + (size_t)c * plane;
    const float* t = targ + (size_t)c * plane;

    const int tid = threadIdx.x;
    v2f loss_acc = {0.f, 0.f};       // .x = ssim, .y = l1
    const float C1v = 0.0001f, C2v = 0.0009f;

    const int oxB  = tid & 31;
    const int oy0B = (tid >> 5) * RY;
    const bool xfast = (blockIdx.x >= 1) && (blockIdx.x <= (W / TX) - 2);

    // prefetch register file: this thread's task (task==tid) for the next tile
    float4 PF_P[5], PF_T[5];

    // issue the 10 global float4 loads for tile s, task==tid (fast path only;
    // boundary rows/blocks keep the inline guarded path in do_task)
    auto issue_pf = [&](const int s) {
        const int ntask = (s == 0) ? NTASK0 : NTASK1;
        const int rowoff = (s == 0) ? 0 : 2 * PAD;
        const int r  = tid >> 3;
        const int cx = tid & 7;
        const int gy = base + TY * s - PAD + rowoff + r;
        const int gxs = gx0 + cx * RX - PAD;
        if (tid < ntask && gy >= 0 && gy < H && xfast) {
            const float4* p4 = (const float4*)(p + (size_t)gy * W + (gxs - 3));
            const float4* t4 = (const float4*)(t + (size_t)gy * W + (gxs - 3));
            #pragma unroll
            for (int i = 0; i < 5; ++i) { PF_P[i] = p4[i]; PF_T[i] = t4[i]; }
        }
    };

    // full h-conv task: loads (or prefetched regs) -> 11-tap -> LDS row
    auto do_task = [&](const int task, const int s, const bool use_pf) {
        const int r  = task >> 3;
        const int cx = task & 7;
        const int rr = ((s == 0) ? 0 : 2 * PAD) + r;     // LDS buffer row
        const int gy = base + TY * s - PAD + rr;         // global image row
        const int gxs = gx0 + cx * RX - PAD;             // input window e=0..13
        const bool rowok   = (gy >= 0) && (gy < H);
        const bool own_row = (gy >= base) && (gy < base + TY * NY);

        float4 P[5], T[5];
        if (rowok && xfast) {
            if (use_pf) {
                #pragma unroll
                for (int i = 0; i < 5; ++i) { P[i] = PF_P[i]; T[i] = PF_T[i]; }
            } else {
                const float4* p4 = (const float4*)(p + (size_t)gy * W + (gxs - 3));
                const float4* t4 = (const float4*)(t + (size_t)gy * W + (gxs - 3));
                #pragma unroll
                for (int i = 0; i < 5; ++i) { P[i] = p4[i]; T[i] = t4[i]; }
            }
        } else if (rowok) {
            const size_t rowoff2 = (size_t)gy * W;
            #pragma unroll
            for (int i = 0; i < 5; ++i) {
                float pe[4], te[4];
                #pragma unroll
                for (int q = 0; q < 4; ++q) {
                    int gx = gxs - 3 + 4 * i + q;
                    bool ok = (gx >= 0) && (gx < W);
                    pe[q] = ok ? p[rowoff2 + gx] : 0.f;
                    te[q] = ok ? t[rowoff2 + gx] : 0.f;
                }
                P[i] = make_float4(pe[0], pe[1], pe[2], pe[3]);
                T[i] = make_float4(te[0], te[1], te[2], te[3]);
            }
        } else {
            #pragma unroll
            for (int i = 0; i < 5; ++i) {
                P[i] = make_float4(0.f, 0.f, 0.f, 0.f);
                T[i] = make_float4(0.f, 0.f, 0.f, 0.f);
            }
        }

        v2f h_sd[RX], h_qq[RX];
        #pragma unroll
        for (int j = 0; j < RX; ++j) {
            h_sd[j] = (v2f){0.f, 0.f};
            h_qq[j] = (v2f){0.f, 0.f};
        }
        #pragma unroll
        for (int e = 0; e < SEG; ++e) {
            const int ii = (e + 3) >> 2, qq = (e + 3) & 3;
            const float pe = (qq == 0) ? P[ii].x : (qq == 1) ? P[ii].y
                            : (qq == 2) ? P[ii].z : P[ii].w;
            const float te = (qq == 0) ? T[ii].x : (qq == 1) ? T[ii].y
                            : (qq == 2) ? T[ii].z : T[ii].w;
            v2f vsd; vsd.x = pe + te; vsd.y = pe - te;
            const v2f vsq = vsd * vsd;          // v_pk_mul_f32
            #pragma unroll
            for (int j = 0; j < RX; ++j) {
                const int k = e - j;
                if (k >= 0 && k < WSZ) {
                    const float wv = wt.w[k];
                    h_sd[j] += wv * vsd;        // v_pk_fma_f32
                    h_qq[j] += wv * vsq;        // v_pk_fma_f32
                }
            }
            // L1 on owned pixels: d = p - t already in vsd.y
            if (e >= PAD && e < PAD + RX && own_row)
                loss_acc.y += fabsf(vsd.y);
        }
        const int xb = cx * RX;
        #pragma unroll
        for (int j = 0; j < RX; ++j)
            sHA[rr][xb + j] = make_float4(h_sd[j].x, h_sd[j].y,
                                          h_qq[j].x, h_qq[j].y);
    };

    // prologue: prefetch tile 0's primary tasks
    issue_pf(0);

    for (int s = 0; s < NY; ++s) {
        // ============ Phase A0 (s>0): shift halo rows 24..33 -> 0..9 =======
        if (s > 0) {
            for (int i = tid; i < 2 * PAD * TX; i += 256) {
                const int dr = i >> 5, cc = i & 31;
                sHA[dr][cc] = sHA[dr + TY][cc];
            }
            __syncthreads();
        }

        // ============ Phase A: h-conv from prefetched regs -> LDS ==========
        {
            const int ntask = (s == 0) ? NTASK0 : NTASK1;
            if (tid < ntask) do_task(tid, s, true);
            // s==0 second round (16 tasks): inline loads, one-time cost
            if (s == 0 && tid < NTASK0 - 256) do_task(tid + 256, 0, false);
        }
        __syncthreads();

        // ============ prefetch next tile (latency hides under Phase B) =====
        if (s + 1 < NY) issue_pf(s + 1);

        // ============ Phase B: vertical 11-tap + SSIM ======================
        {
            v2f mu[RY], qq[RY];
            #pragma unroll
            for (int j = 0; j < RY; ++j) {
                mu[j] = (v2f){0.f, 0.f};
                qq[j] = (v2f){0.f, 0.f};
            }
            #pragma unroll
            for (int k = 0; k < RY + 2 * PAD; ++k) {
                const float4 f = sHA[oy0B + k][oxB];
                v2f fsd; fsd.x = f.x; fsd.y = f.y;
                v2f fsq; fsq.x = f.z; fsq.y = f.w;
                #pragma unroll
                for (int j = 0; j < RY; ++j) {
                    const int kk = k - j;
                    if (kk >= 0 && kk < WSZ) {
                        const float wv = wt.w[kk];
                        mu[j] += wv * fsd;          // v_pk_fma_f32
                        qq[j] += wv * fsq;          // v_pk_fma_f32
                    }
                }
            }
            #pragma unroll
            for (int j = 0; j < RY; ++j) {
                const v2f musq = mu[j] * mu[j];     // (S^2, D^2)  v_pk_mul
                const v2f rr2  = qq[j] - musq;      // (Qs-S^2, Qd-D^2)
                const float a    = 0.5f * (musq.x - musq.y) + C1v;
                const float b    = 0.5f * (rr2.x - rr2.y) + C2v;
                const float cden = 0.5f * (musq.x + musq.y) + C1v;
                const float dden = 0.5f * (rr2.x + rr2.y) + C2v;
                loss_acc.x += (a * b) * __builtin_amdgcn_rcpf(cden * dden);
            }
        }
        __syncthreads();   // also drains the prefetch loads (free by now)
    }

    // ============ block reduction -> contention-free partial ================
    #pragma unroll
    for (int off = 32; off > 0; off >>= 1) {
        loss_acc.x += __shfl_down(loss_acc.x, off, 64);
        loss_acc.y += __shfl_down(loss_acc.y, off, 64);
    }
    __shared__ float red[2][4];
    const int lane = tid & 63;
    const int wid  = tid >> 6;
    if (lane == 0) { red[0][wid] = loss_acc.x; red[1][wid] = loss_acc.y; }
    __syncthreads();
    if (tid == 0) {
        const float sv = red[0][0] + red[0][1] + red[0][2] + red[0][3];
        const float lv = red[1][0] + red[1][1] + red[1][2] + red[1][3];
        const int bid = (blockIdx.z * gridDim.y + blockIdx.y) * gridDim.x + blockIdx.x;
        partials[bid] = make_float2(sv, lv);
    }
}

__global__ __launch_bounds__(256) void finalize_kernel(
    const float2* __restrict__ partials, int n,
    float* __restrict__ out, double invN)
{
    const int tid = threadIdx.x;
    double s = 0.0, l = 0.0;
    for (int i = tid; i < n; i += 256) {
        float2 v = partials[i];
        s += (double)v.x;
        l += (double)v.y;
    }
    #pragma unroll
    for (int off = 32; off > 0; off >>= 1) {
        s += __shfl_down(s, off, 64);
        l += __shfl_down(l, off, 64);
    }
    __shared__ double rs[4], rl[4];
    const int lane = tid & 63, wid = tid >> 6;
    if (lane == 0) { rs[wid] = s; rl[wid] = l; }
    __syncthreads();
    if (tid == 0) {
        const double st = rs[0] + rs[1] + rs[2] + rs[3];
        const double lt = rl[0] + rl[1] + rl[2] + rl[3];
        out[0] = (float)(0.8 * lt * invN + 0.2 * (1.0 - st * invN));
    }
}

extern "C" void kernel_launch(void* const* d_in, const int* in_sizes, int n_in,
                              void* d_out, int out_size, void* d_ws, size_t ws_size,
                              hipStream_t stream)
{
    const float* pred = (const float*)d_in[0];
    const float* targ = (const float*)d_in[1];
    float* out = (float*)d_out;
    float2* partials = (float2*)d_ws;

    const int C = 3, H = 2160, W = 3840;

    W11 wt;
    double g[WSZ], sg = 0.0;
    for (int i = 0; i < WSZ; ++i) {
        double d = (double)i - (WSZ / 2);
        g[i] = exp(-(d * d) / (2.0 * 1.5 * 1.5));
        sg += g[i];
    }
    for (int i = 0; i < WSZ; ++i) wt.w[i] = (float)(g[i] / sg);

    dim3 grid(W / TX, H / (TY * NY), C);   // 120 x 15 x 3 = 5400 blocks
    ssim_l1_kernel<<<grid, 256, 0, stream>>>(pred, targ, wt, partials);

    const int nblocks = (W / TX) * (H / (TY * NY)) * C;
    double invN = 1.0 / ((double)C * (double)H * (double)W);
    finalize_kernel<<<1, 256, 0, stream>>>(partials, nblocks, out, invN);
}

// Round 9
// 259.018 us; speedup vs baseline: 1.1137x; 1.1137x over previous
//
#include <hip/hip_runtime.h>
#include <math.h>

#define WSZ 11
#define PAD 5
#define TX 32
#define TY 12
#define NY 12                // y-tiles per block: 144 rows/block, 2160/144 = 15
#define IY (TY + 2*PAD)      // 22
#define RX 4                 // h-pass: 4 output px per task
#define NTASK0 (IY * 8)      // 176 tasks (s==0: full 22 rows)
#define NTASK1 (TY * 8)      // 96 tasks (s>0: only 12 new rows)
#define SEG (RX + 2*PAD)     // 14 input floats per task
#define RY 3                 // v-pass rows per thread (4 groups x 3 = 12)
#define SA 33                // sHA row stride in float4 (odd -> rotating banks)
#define NTHR 128

typedef float v2f __attribute__((ext_vector_type(2)));

struct W11 { float w[WSZ]; };

// R11 math/structure (sum/diff 4-channel, rolling halo, 2 pk_fma/tap) with a
// HALVED SYNC DOMAIN. R11-R16 series read as one dataset: every variant that
// enlarged the barrier group (R13: 8 waves) or cut independent groups/CU
// (R12/R15: 4) lost; per-px work is constant and time ~ 1/issue-efficiency.
// Surviving theory: waves inside a block move through phases in lockstep, so
// issue-mix diversity comes only from BETWEEN blocks. R17: 128-thread blocks
// (2-wave barrier groups), TY=12/NY=12 -> LDS 11.6 KB -> ~13 blocks/CU in
// ~13 independent groups (vs 4.6 groups of 4 waves). Per-pixel VALU, LDS
// traffic, fetch and write patterns are bit-identical to R11.
__global__ __launch_bounds__(NTHR, 6) void ssim_l1_kernel(
    const float* __restrict__ pred, const float* __restrict__ targ,
    W11 wt, float2* __restrict__ partials)
{
    constexpr int H = 2160, W = 3840;
    __shared__ float4 sHA[IY][SA];   // {hs, hd, hss, hdd}   11.6 KB

    const int c    = blockIdx.z;
    const int gx0  = blockIdx.x * TX;
    const int base = blockIdx.y * (TY * NY);   // first output row of block
    const size_t plane = (size_t)H * W;
    const float* p = pred + (size_t)c * plane;
    const float* t = targ + (size_t)c * plane;

    const int tid = threadIdx.x;
    v2f loss_acc = {0.f, 0.f};       // .x = ssim, .y = l1
    const float C1v = 0.0001f, C2v = 0.0009f;

    const int oxB  = tid & 31;
    const int oy0B = (tid >> 5) * RY;      // 4 y-groups x RY=3 rows
    const bool xfast = (blockIdx.x >= 1) && (blockIdx.x <= (W / TX) - 2);

    for (int s = 0; s < NY; ++s) {
        // ============ Phase A0 (s>0): shift halo rows 12..21 -> 0..9 =======
        if (s > 0) {
            for (int i = tid; i < 2 * PAD * TX; i += NTHR) {   // 320 float4
                const int dr = i >> 5, cc = i & 31;
                sHA[dr][cc] = sHA[dr + TY][cc];
            }
            __syncthreads();
        }

        // ============ Phase A: horizontal 11-tap, global -> LDS ============
        const int ntask  = (s == 0) ? NTASK0 : NTASK1;
        const int rowoff = (s == 0) ? 0 : 2 * PAD;
        const int gyA    = base + TY * s - PAD;      // gy = gyA + rr
        for (int task = tid; task < ntask; task += NTHR) {
            const int r  = task >> 3;
            const int cx = task & 7;
            const int rr = rowoff + r;               // LDS buffer row
            const int gy = gyA + rr;                 // global image row
            const int gxs = gx0 + cx * RX - PAD;     // input window e=0..13
            const bool rowok   = (gy >= 0) && (gy < H);
            const bool own_row = (gy >= base) && (gy < base + TY * NY);

            // 5 aligned float4 per image covering gxs-3 .. gxs+16 (registers)
            float4 P[5], T[5];
            if (rowok && xfast) {
                const float4* p4 = (const float4*)(p + (size_t)gy * W + (gxs - 3));
                const float4* t4 = (const float4*)(t + (size_t)gy * W + (gxs - 3));
                #pragma unroll
                for (int i = 0; i < 5; ++i) { P[i] = p4[i]; T[i] = t4[i]; }
            } else if (rowok) {
                const size_t rowoff2 = (size_t)gy * W;
                #pragma unroll
                for (int i = 0; i < 5; ++i) {
                    float pe[4], te[4];
                    #pragma unroll
                    for (int q = 0; q < 4; ++q) {
                        int gx = gxs - 3 + 4 * i + q;
                        bool ok = (gx >= 0) && (gx < W);
                        pe[q] = ok ? p[rowoff2 + gx] : 0.f;
                        te[q] = ok ? t[rowoff2 + gx] : 0.f;
                    }
                    P[i] = make_float4(pe[0], pe[1], pe[2], pe[3]);
                    T[i] = make_float4(te[0], te[1], te[2], te[3]);
                }
            } else {
                #pragma unroll
                for (int i = 0; i < 5; ++i) {
                    P[i] = make_float4(0.f, 0.f, 0.f, 0.f);
                    T[i] = make_float4(0.f, 0.f, 0.f, 0.f);
                }
            }

            v2f h_sd[RX], h_qq[RX];
            #pragma unroll
            for (int j = 0; j < RX; ++j) {
                h_sd[j] = (v2f){0.f, 0.f};
                h_qq[j] = (v2f){0.f, 0.f};
            }
            #pragma unroll
            for (int e = 0; e < SEG; ++e) {
                const int ii = (e + 3) >> 2, qq = (e + 3) & 3;
                const float pe = (qq == 0) ? P[ii].x : (qq == 1) ? P[ii].y
                                : (qq == 2) ? P[ii].z : P[ii].w;
                const float te = (qq == 0) ? T[ii].x : (qq == 1) ? T[ii].y
                                : (qq == 2) ? T[ii].z : T[ii].w;
                v2f vsd; vsd.x = pe + te; vsd.y = pe - te;
                const v2f vsq = vsd * vsd;          // v_pk_mul_f32
                #pragma unroll
                for (int j = 0; j < RX; ++j) {
                    const int k = e - j;
                    if (k >= 0 && k < WSZ) {
                        const float wv = wt.w[k];
                        h_sd[j] += wv * vsd;        // v_pk_fma_f32
                        h_qq[j] += wv * vsq;        // v_pk_fma_f32
                    }
                }
                // L1 on owned pixels: d = p - t already in vsd.y
                if (e >= PAD && e < PAD + RX && own_row)
                    loss_acc.y += fabsf(vsd.y);
            }
            const int xb = cx * RX;
            #pragma unroll
            for (int j = 0; j < RX; ++j)
                sHA[rr][xb + j] = make_float4(h_sd[j].x, h_sd[j].y,
                                              h_qq[j].x, h_qq[j].y);
        }
        __syncthreads();

        // ============ Phase B: vertical 11-tap + SSIM ======================
        {
            v2f mu[RY], qq[RY];
            #pragma unroll
            for (int j = 0; j < RY; ++j) {
                mu[j] = (v2f){0.f, 0.f};
                qq[j] = (v2f){0.f, 0.f};
            }
            #pragma unroll
            for (int k = 0; k < RY + 2 * PAD; ++k) {   // 13 contiguous reads
                const float4 f = sHA[oy0B + k][oxB];
                v2f fsd; fsd.x = f.x; fsd.y = f.y;
                v2f fsq; fsq.x = f.z; fsq.y = f.w;
                #pragma unroll
                for (int j = 0; j < RY; ++j) {
                    const int kk = k - j;
                    if (kk >= 0 && kk < WSZ) {
                        const float wv = wt.w[kk];
                        mu[j] += wv * fsd;          // v_pk_fma_f32
                        qq[j] += wv * fsq;          // v_pk_fma_f32
                    }
                }
            }
            #pragma unroll
            for (int j = 0; j < RY; ++j) {
                const v2f musq = mu[j] * mu[j];     // (S^2, D^2)  v_pk_mul
                const v2f rr2  = qq[j] - musq;      // (Qs-S^2, Qd-D^2)
                const float a    = 0.5f * (musq.x - musq.y) + C1v;
                const float b    = 0.5f * (rr2.x - rr2.y) + C2v;
                const float cden = 0.5f * (musq.x + musq.y) + C1v;
                const float dden = 0.5f * (rr2.x + rr2.y) + C2v;
                loss_acc.x += (a * b) * __builtin_amdgcn_rcpf(cden * dden);
            }
        }
        __syncthreads();   // Phase B reads done before next shift/Phase A
    }

    // ============ block reduction -> contention-free partial ================
    #pragma unroll
    for (int off = 32; off > 0; off >>= 1) {
        loss_acc.x += __shfl_down(loss_acc.x, off, 64);
        loss_acc.y += __shfl_down(loss_acc.y, off, 64);
    }
    __shared__ float red[2][2];
    const int lane = tid & 63;
    const int wid  = tid >> 6;
    if (lane == 0) { red[0][wid] = loss_acc.x; red[1][wid] = loss_acc.y; }
    __syncthreads();
    if (tid == 0) {
        const float sv = red[0][0] + red[0][1];
        const float lv = red[1][0] + red[1][1];
        const int bid = (blockIdx.z * gridDim.y + blockIdx.y) * gridDim.x + blockIdx.x;
        partials[bid] = make_float2(sv, lv);
    }
}

__global__ __launch_bounds__(256) void finalize_kernel(
    const float2* __restrict__ partials, int n,
    float* __restrict__ out, double invN)
{
    const int tid = threadIdx.x;
    double s = 0.0, l = 0.0;
    for (int i = tid; i < n; i += 256) {
        float2 v = partials[i];
        s += (double)v.x;
        l += (double)v.y;
    }
    #pragma unroll
    for (int off = 32; off > 0; off >>= 1) {
        s += __shfl_down(s, off, 64);
        l += __shfl_down(l, off, 64);
    }
    __shared__ double rs[4], rl[4];
    const int lane = tid & 63, wid = tid >> 6;
    if (lane == 0) { rs[wid] = s; rl[wid] = l; }
    __syncthreads();
    if (tid == 0) {
        const double st = rs[0] + rs[1] + rs[2] + rs[3];
        const double lt = rl[0] + rl[1] + rl[2] + rl[3];
        out[0] = (float)(0.8 * lt * invN + 0.2 * (1.0 - st * invN));
    }
}

extern "C" void kernel_launch(void* const* d_in, const int* in_sizes, int n_in,
                              void* d_out, int out_size, void* d_ws, size_t ws_size,
                              hipStream_t stream)
{
    const float* pred = (const float*)d_in[0];
    const float* targ = (const float*)d_in[1];
    float* out = (float*)d_out;
    float2* partials = (float2*)d_ws;

    const int C = 3, H = 2160, W = 3840;

    W11 wt;
    double g[WSZ], sg = 0.0;
    for (int i = 0; i < WSZ; ++i) {
        double d = (double)i - (WSZ / 2);
        g[i] = exp(-(d * d) / (2.0 * 1.5 * 1.5));
        sg += g[i];
    }
    for (int i = 0; i < WSZ; ++i) wt.w[i] = (float)(g[i] / sg);

    dim3 grid(W / TX, H / (TY * NY), C);   // 120 x 15 x 3 = 5400 blocks
    ssim_l1_kernel<<<grid, NTHR, 0, stream>>>(pred, targ, wt, partials);

    const int nblocks = (W / TX) * (H / (TY * NY)) * C;
    double invN = 1.0 / ((double)C * (double)H * (double)W);
    finalize_kernel<<<1, 256, 0, stream>>>(partials, nblocks, out, invN);
}

// Round 10
// 252.076 us; speedup vs baseline: 1.1443x; 1.0275x over previous
//
#include <hip/hip_runtime.h>
#include <math.h>

#define WSZ 11
#define PAD 5
#define TX 32
#define TY 16                // rows per tile
#define NY 9                 // 144 rows/block, 2160/144 = 15
#define IY (TY + 2*PAD)      // 26
#define RX 4                 // h-pass: 4 output px per task
#define SEG (RX + 2*PAD)     // 14 input floats per task
#define RYC 4                // consumer rows per thread (4 groups x 4 = 16)
#define SA 33                // sH row stride in float4 (odd -> rotating banks)

typedef float v2f __attribute__((ext_vector_type(2)));

struct W11 { float w[WSZ]; };

// R11 math (sum/diff 4-channel, 2 pk_fma/tap, rolling halo) + R18 wave-role
// specialization. R11-R17: seven structural variants, identical per-px math,
// all pinned at VALUBusy 44-53%; eliminated = conflicts, LDS traffic,
// occupancy, lane fill, barrier count, barrier granularity. Surviving theory:
// BARRIER LOCKSTEP CORRELATES PIPE DEMAND - every wave alternates VALU-burst
// (Phase A) and LDS-burst (Phase B), so each pipe idles ~half the time. R18:
// waves 0-1 = pure producers (VMEM + h-conv VALU + LDS writes, stage tile
// s+1), waves 2-3 = pure consumers (LDS reads + v-conv + SSIM, drain tile s),
// double-buffered, ONE barrier/tile. Both flavors co-resident -> VALU and
// LDS pipes fed simultaneously; VMEM latency hides under consumer work.
// Perfect fill both roles: producers 128 tasks (16 rows x 8), consumers
// 128 threads x 4 rows. Per-px instruction streams bit-identical to R11.
__global__ __launch_bounds__(256, 4) void ssim_l1_kernel(
    const float* __restrict__ pred, const float* __restrict__ targ,
    W11 wt, float2* __restrict__ partials)
{
    constexpr int H = 2160, W = 3840;
    __shared__ float4 sH[2][IY][SA];   // {hs, hd, hss, hdd} x2   27.5 KB

    const int c    = blockIdx.z;
    const int gx0  = blockIdx.x * TX;
    const int base = blockIdx.y * (TY * NY);   // first output row of block
    const size_t plane = (size_t)H * W;
    const float* p = pred + (size_t)c * plane;
    const float* t = targ + (size_t)c * plane;

    const int tid = threadIdx.x;
    v2f loss_acc = {0.f, 0.f};       // .x = ssim, .y = l1
    const float C1v = 0.0001f, C2v = 0.0009f;
    const bool xfast = (blockIdx.x >= 1) && (blockIdx.x <= (W / TX) - 2);

    // one horizontal 11-tap task: image row gy, x-chunk cx -> dst[rr][..]
    auto hconv = [&](float4 (*__restrict__ dst)[SA], const int rr,
                     const int gy, const int cx) {
        const int gxs = gx0 + cx * RX - PAD;         // input window e=0..13
        const bool rowok   = (gy >= 0) && (gy < H);
        const bool own_row = (gy >= base) && (gy < base + TY * NY);

        float4 P[5], T[5];
        if (rowok && xfast) {
            const float4* p4 = (const float4*)(p + (size_t)gy * W + (gxs - 3));
            const float4* t4 = (const float4*)(t + (size_t)gy * W + (gxs - 3));
            #pragma unroll
            for (int i = 0; i < 5; ++i) { P[i] = p4[i]; T[i] = t4[i]; }
        } else if (rowok) {
            const size_t rowoff2 = (size_t)gy * W;
            #pragma unroll
            for (int i = 0; i < 5; ++i) {
                float pe[4], te[4];
                #pragma unroll
                for (int q = 0; q < 4; ++q) {
                    int gx = gxs - 3 + 4 * i + q;
                    bool ok = (gx >= 0) && (gx < W);
                    pe[q] = ok ? p[rowoff2 + gx] : 0.f;
                    te[q] = ok ? t[rowoff2 + gx] : 0.f;
                }
                P[i] = make_float4(pe[0], pe[1], pe[2], pe[3]);
                T[i] = make_float4(te[0], te[1], te[2], te[3]);
            }
        } else {
            #pragma unroll
            for (int i = 0; i < 5; ++i) {
                P[i] = make_float4(0.f, 0.f, 0.f, 0.f);
                T[i] = make_float4(0.f, 0.f, 0.f, 0.f);
            }
        }

        v2f h_sd[RX], h_qq[RX];
        #pragma unroll
        for (int j = 0; j < RX; ++j) {
            h_sd[j] = (v2f){0.f, 0.f};
            h_qq[j] = (v2f){0.f, 0.f};
        }
        #pragma unroll
        for (int e = 0; e < SEG; ++e) {
            const int ii = (e + 3) >> 2, qq = (e + 3) & 3;
            const float pe = (qq == 0) ? P[ii].x : (qq == 1) ? P[ii].y
                            : (qq == 2) ? P[ii].z : P[ii].w;
            const float te = (qq == 0) ? T[ii].x : (qq == 1) ? T[ii].y
                            : (qq == 2) ? T[ii].z : T[ii].w;
            v2f vsd; vsd.x = pe + te; vsd.y = pe - te;
            const v2f vsq = vsd * vsd;          // v_pk_mul_f32
            #pragma unroll
            for (int j = 0; j < RX; ++j) {
                const int k = e - j;
                if (k >= 0 && k < WSZ) {
                    const float wv = wt.w[k];
                    h_sd[j] += wv * vsd;        // v_pk_fma_f32
                    h_qq[j] += wv * vsq;        // v_pk_fma_f32
                }
            }
            // L1 on owned pixels (each image row h-conv'd exactly once)
            if (e >= PAD && e < PAD + RX && own_row)
                loss_acc.y += fabsf(vsd.y);
        }
        const int xb = cx * RX;
        #pragma unroll
        for (int j = 0; j < RX; ++j)
            dst[rr][xb + j] = make_float4(h_sd[j].x, h_sd[j].y,
                                          h_qq[j].x, h_qq[j].y);
    };

    // ============ prologue: ALL waves fill buffer 0 (26 rows, 208 tasks) ====
    if (tid < IY * 8) {
        const int r = tid >> 3, cx = tid & 7;
        hconv(sH[0], r, base - PAD + r, cx);
    }
    __syncthreads();

    for (int s = 0; s < NY; ++s) {
        float4 (*cur)[SA] = sH[s & 1];
        float4 (*nxt)[SA] = sH[(s & 1) ^ 1];

        if (tid < 128) {
            // ================= PRODUCER waves: stage tile s+1 ==============
            if (s < NY - 1) {
                // halo: cur rows 16..25 (hr 16s+16..16s+25) -> nxt rows 0..9
                for (int i = tid; i < 2 * PAD * TX; i += 128) {  // 320 float4
                    const int dr = i >> 5, cc = i & 31;
                    nxt[dr][cc] = cur[TY + dr][cc];
                }
                // 16 new h-rows: nxt rows 10..25, gy = base-5+16(s+1)+10+r
                const int r = tid >> 3, cx = tid & 7;
                hconv(nxt, 10 + r, base - PAD + TY * (s + 1) + 10 + r, cx);
            }
        } else {
            // ================= CONSUMER waves: drain tile s ================
            const int oxB = tid & 31;
            const int oy0 = ((tid >> 5) & 3) * RYC;   // 0,4,8,12
            v2f mu[RYC], qq[RYC];
            #pragma unroll
            for (int j = 0; j < RYC; ++j) {
                mu[j] = (v2f){0.f, 0.f};
                qq[j] = (v2f){0.f, 0.f};
            }
            #pragma unroll
            for (int k = 0; k < RYC + 2 * PAD; ++k) {   // 14 contiguous reads
                const float4 f = cur[oy0 + k][oxB];
                v2f fsd; fsd.x = f.x; fsd.y = f.y;
                v2f fsq; fsq.x = f.z; fsq.y = f.w;
                #pragma unroll
                for (int j = 0; j < RYC; ++j) {
                    const int kk = k - j;
                    if (kk >= 0 && kk < WSZ) {
                        const float wv = wt.w[kk];
                        mu[j] += wv * fsd;          // v_pk_fma_f32
                        qq[j] += wv * fsq;          // v_pk_fma_f32
                    }
                }
            }
            #pragma unroll
            for (int j = 0; j < RYC; ++j) {
                const v2f musq = mu[j] * mu[j];     // (S^2, D^2)
                const v2f rr2  = qq[j] - musq;      // (Qs-S^2, Qd-D^2)
                const float a    = 0.5f * (musq.x - musq.y) + C1v;
                const float b    = 0.5f * (rr2.x - rr2.y) + C2v;
                const float cden = 0.5f * (musq.x + musq.y) + C1v;
                const float dden = 0.5f * (rr2.x + rr2.y) + C2v;
                loss_acc.x += (a * b) * __builtin_amdgcn_rcpf(cden * dden);
            }
        }
        // ONE barrier per tile: nxt fully staged before it becomes cur;
        // cur fully drained before it is overwritten as the next nxt.
        __syncthreads();
    }

    // ============ block reduction -> contention-free partial ================
    #pragma unroll
    for (int off = 32; off > 0; off >>= 1) {
        loss_acc.x += __shfl_down(loss_acc.x, off, 64);
        loss_acc.y += __shfl_down(loss_acc.y, off, 64);
    }
    __shared__ float red[2][4];
    const int lane = tid & 63;
    const int wid  = tid >> 6;
    if (lane == 0) { red[0][wid] = loss_acc.x; red[1][wid] = loss_acc.y; }
    __syncthreads();
    if (tid == 0) {
        const float sv = red[0][0] + red[0][1] + red[0][2] + red[0][3];
        const float lv = red[1][0] + red[1][1] + red[1][2] + red[1][3];
        const int bid = (blockIdx.z * gridDim.y + blockIdx.y) * gridDim.x + blockIdx.x;
        partials[bid] = make_float2(sv, lv);
    }
}

__global__ __launch_bounds__(256) void finalize_kernel(
    const float2* __restrict__ partials, int n,
    float* __restrict__ out, double invN)
{
    const int tid = threadIdx.x;
    double s = 0.0, l = 0.0;
    for (int i = tid; i < n; i += 256) {
        float2 v = partials[i];
        s += (double)v.x;
        l += (double)v.y;
    }
    #pragma unroll
    for (int off = 32; off > 0; off >>= 1) {
        s += __shfl_down(s, off, 64);
        l += __shfl_down(l, off, 64);
    }
    __shared__ double rs[4], rl[4];
    const int lane = tid & 63, wid = tid >> 6;
    if (lane == 0) { rs[wid] = s; rl[wid] = l; }
    __syncthreads();
    if (tid == 0) {
        const double st = rs[0] + rs[1] + rs[2] + rs[3];
        const double lt = rl[0] + rl[1] + rl[2] + rl[3];
        out[0] = (float)(0.8 * lt * invN + 0.2 * (1.0 - st * invN));
    }
}

extern "C" void kernel_launch(void* const* d_in, const int* in_sizes, int n_in,
                              void* d_out, int out_size, void* d_ws, size_t ws_size,
                              hipStream_t stream)
{
    const float* pred = (const float*)d_in[0];
    const float* targ = (const float*)d_in[1];
    float* out = (float*)d_out;
    float2* partials = (float2*)d_ws;

    const int C = 3, H = 2160, W = 3840;

    W11 wt;
    double g[WSZ], sg = 0.0;
    for (int i = 0; i < WSZ; ++i) {
        double d = (double)i - (WSZ / 2);
        g[i] = exp(-(d * d) / (2.0 * 1.5 * 1.5));
        sg += g[i];
    }
    for (int i = 0; i < WSZ; ++i) wt.w[i] = (float)(g[i] / sg);

    dim3 grid(W / TX, H / (TY * NY), C);   // 120 x 15 x 3 = 5400 blocks
    ssim_l1_kernel<<<grid, 256, 0, stream>>>(pred, targ, wt, partials);

    const int nblocks = (W / TX) * (H / (TY * NY)) * C;
    double invN = 1.0 / ((double)C * (double)H * (double)W);
    finalize_kernel<<<1, 256, 0, stream>>>(partials, nblocks, out, invN);
}